// Round 5
// baseline (400.935 us; speedup 1.0000x reference)
//
#include <hip/hip_runtime.h>
#include <cstdint>

#define BLK 256
#define EB 4               // edges per thread in bucket (int4 loads)
#define SLB 6              // slice = 64 nodes
#define SLN 64
#define SCAP 1536          // mean 1024 @ E=1.6M/NS=1563; +16 sigma margin
#define CURS 16            // cur counter stride (64B) -> no same-line atomic ping-pong

// Fixed-point scales for integer atomics (R2/R3 lesson: FP atomicAdd on LDS
// lowers to a CAS retry loop on gfx950 -> 9x stall; int ds_add_u32 /
// global_atomic_add are native).
#define S1   2097152.0f        // 2^21, layer-1/2 feature accumulators
#define IS1  (1.0f / 2097152.0f)
#define DSC  16777216.0f       // 2^24, degree accumulator
#define IDSC (1.0f / 16777216.0f)

__device__ inline unsigned short f2bf(float f) {  // RNE
  unsigned u = __float_as_uint(f);
  return (unsigned short)((u + 0x7FFF + ((u >> 16) & 1)) >> 16);
}
__device__ inline float bflo(unsigned u) { return __uint_as_float(u << 16); }
__device__ inline float bfhi(unsigned u) { return __uint_as_float(u & 0xFFFF0000u); }

// ---------------- init per-slice cursors + zero degree array ----------------
__global__ __launch_bounds__(BLK) void k_zero(int* __restrict__ cur,
                                              int* __restrict__ degI,
                                              int n, int NS) {
  int i = blockIdx.x * BLK + threadIdx.x;
  if (i < NS) cur[i * CURS] = i * SCAP;
  if (i < n) degI[i] = 0;
}

// ---------------- bucket edges into fixed-capacity slice bins ----------------
// bpk[p] = { (dstLocal<<20) | src, ew }   (requires n <= 2^20, dstLocal < 64)
// v2 (R4 lesson: LDS-count version was grid-limited to 391 blocks -> 14%
// occupancy, pure latency stall): per-edge direct global atomic reservation,
// 4 edges/thread with coalesced int4 loads, grid 1563 -> ~24 waves/CU.
__global__ __launch_bounds__(BLK) void k_bucket(const int* __restrict__ src,
                                                const int* __restrict__ dst,
                                                const float* __restrict__ ew,
                                                int* __restrict__ cur,
                                                int2* __restrict__ bpk,
                                                int* __restrict__ degI,
                                                int n, int E) {
  int t = blockIdx.x * BLK + threadIdx.x;
  int base = t * EB;
  if (base >= E) return;
  if (base + EB <= E) {
    int4   d4 = *(const int4*)(dst + base);
    int4   s4 = *(const int4*)(src + base);
    float4 w4 = *(const float4*)(ew + base);
    int   dd[EB] = {d4.x, d4.y, d4.z, d4.w};
    int   ss[EB] = {s4.x, s4.y, s4.z, s4.w};
    float ww[EB] = {w4.x, w4.y, w4.z, w4.w};
    int p[EB], sl[EB];
    bool ok[EB];
#pragma unroll
    for (int k = 0; k < EB; k++) {   // phase A: issue all reservations (MLP)
      ok[k] = (unsigned)dd[k] < (unsigned)n;
      sl[k] = dd[k] >> SLB;
      p[k] = ok[k] ? atomicAdd(&cur[sl[k] * CURS], 1) : 0;
    }
#pragma unroll
    for (int k = 0; k < EB; k++) {   // phase B: clamp + store + degree
      if (ok[k]) {
        int pp = min(max(p[k], sl[k] * SCAP), (sl[k] + 1) * SCAP - 1);
        int packed = ((dd[k] & (SLN - 1)) << 20) | (ss[k] & 0xFFFFF);
        bpk[pp] = make_int2(packed, __float_as_int(ww[k]));
        atomicAdd(&degI[dd[k]], __float2int_rn(ww[k] * DSC));
      }
    }
  } else {
    for (int idx = base; idx < E; idx++) {
      int d = dst[idx];
      if ((unsigned)d >= (unsigned)n) continue;
      int s = d >> SLB;
      int p = atomicAdd(&cur[s * CURS], 1);
      p = min(max(p, s * SCAP), (s + 1) * SCAP - 1);
      float w = ew[idx];
      bpk[p] = make_int2(((d & (SLN - 1)) << 20) | (src[idx] & 0xFFFFF),
                         __float_as_int(w));
      atomicAdd(&degI[d], __float2int_rn(w * DSC));
    }
  }
}

// ---------------- GEMM1: h1s[n,64](bf16x2) = dinv * (x[n,128] @ W1[128,64]) --
__global__ __launch_bounds__(BLK) void k_gemm1(const float* __restrict__ x,
                                               const float* __restrict__ W,
                                               const int* __restrict__ degI,
                                               unsigned* __restrict__ h1s, int n) {
  __shared__ float Ws[128 * 64];
  __shared__ float xs[16][128];
  int tid = threadIdx.x;
  const float4* W4 = (const float4*)W;
  float4* Ws4 = (float4*)Ws;
#pragma unroll
  for (int i = 0; i < 8; i++) Ws4[tid + i * BLK] = W4[tid + i * BLK];
  int row0 = blockIdx.x * 16;
  int nrows = min(16, n - row0);
  const float4* x4 = (const float4*)(x + (size_t)row0 * 128);
  float4* xs4 = (float4*)xs;
  for (int i = tid; i < nrows * 32; i += BLK) xs4[i] = x4[i];
  __syncthreads();
  int col = tid & 63, rg = tid >> 6;  // wave-uniform rg -> xs reads broadcast
  float acc0 = 0.f, acc1 = 0.f, acc2 = 0.f, acc3 = 0.f;
#pragma unroll 4
  for (int k = 0; k < 128; k++) {
    float w = Ws[k * 64 + col];
    acc0 += xs[rg][k] * w;
    acc1 += xs[rg + 4][k] * w;
    acc2 += xs[rg + 8][k] * w;
    acc3 += xs[rg + 12][k] * w;
  }
  int r = row0 + rg;
  int rc0 = min(r, n - 1), rc1 = min(r + 4, n - 1),
      rc2 = min(r + 8, n - 1), rc3 = min(r + 12, n - 1);
  float d0 = rsqrtf(1.0f + degI[rc0] * IDSC), d1 = rsqrtf(1.0f + degI[rc1] * IDSC),
        d2 = rsqrtf(1.0f + degI[rc2] * IDSC), d3 = rsqrtf(1.0f + degI[rc3] * IDSC);
  float v0 = acc0 * d0, v1 = acc1 * d1, v2 = acc2 * d2, v3 = acc3 * d3;
  float p0 = __shfl_xor(v0, 1, 64), p1 = __shfl_xor(v1, 1, 64),
        p2 = __shfl_xor(v2, 1, 64), p3 = __shfl_xor(v3, 1, 64);
  if ((col & 1) == 0) {
    int dw = col >> 1;
    unsigned u0 = (unsigned)f2bf(v0) | ((unsigned)f2bf(p0) << 16);
    unsigned u1 = (unsigned)f2bf(v1) | ((unsigned)f2bf(p1) << 16);
    unsigned u2 = (unsigned)f2bf(v2) | ((unsigned)f2bf(p2) << 16);
    unsigned u3 = (unsigned)f2bf(v3) | ((unsigned)f2bf(p3) << 16);
    if (r < n)      h1s[(size_t)r * 32 + dw]        = u0;
    if (r + 4 < n)  h1s[(size_t)(r + 4) * 32 + dw]  = u1;
    if (r + 8 < n)  h1s[(size_t)(r + 8) * 32 + dw]  = u2;
    if (r + 12 < n) h1s[(size_t)(r + 12) * 32 + dw] = u3;
  }
}

// ---------------- layer-1: slice-LDS aggregate + bias + ReLU + GEMM2 --------
// Block = slice of 64 nodes (R3's measured-best geometry). Half-wave per edge,
// lane owns dword d (feats 2d,2d+1). Fixed-point int accumulators in LDS
// (native ds_add_u32), two planes (even/odd feat), stride 33.
#define U1 8
__global__ __launch_bounds__(BLK) void k_agg1s(const int* __restrict__ degI,
                                               const int2* __restrict__ bpk,
                                               const int* __restrict__ cur,
                                               const unsigned* __restrict__ h1s,
                                               const float* __restrict__ b1,
                                               const float* __restrict__ W2,
                                               unsigned* __restrict__ h2s, int n) {
  __shared__ int accE[SLN * 33];
  __shared__ int accO[SLN * 33];
  __shared__ float W2s[64 * 16];
  __shared__ float dv[SLN];
  __shared__ float bb[64];
  int tid = threadIdx.x;
  int s = blockIdx.x;
  int node0 = s << SLB;
  int sn = min(SLN, n - node0);
  for (int i = tid; i < SLN * 33; i += BLK) { accE[i] = 0; accO[i] = 0; }
  for (int i = tid; i < 1024; i += BLK) W2s[i] = W2[i];
  if (tid < SLN)
    dv[tid] = (tid < sn) ? rsqrtf(1.0f + degI[node0 + tid] * IDSC) : 0.f;
  if (tid < 64) bb[tid] = b1[tid];
  int e0 = s * SCAP;
  int cnt = min(cur[s * CURS], e0 + SCAP) - e0;
  __syncthreads();

  int w = tid >> 6, half = (tid >> 5) & 1, d = tid & 31;
  unsigned nm1 = (unsigned)(n - 1);
  const int WED = 2 * U1;    // 16 edges per wave per iter
  const int STEP = 4 * WED;  // 64 per block-iter
  for (int base = w * WED; base < cnt; base += STEP) {
    int2 pk[U1];
    float wt[U1];
    unsigned g[U1];
#pragma unroll
    for (int u = 0; u < U1; u++) {
      int e = base + 2 * u + half;
      pk[u] = bpk[e0 + min(e, cnt - 1)];  // in-slice clamp (loop ran => cnt>0)
      wt[u] = (e < cnt) ? __int_as_float(pk[u].y) : 0.f;
    }
#pragma unroll
    for (int u = 0; u < U1; u++)
      g[u] = h1s[(size_t)min((unsigned)(pk[u].x & 0xFFFFF), nm1) * 32 + d];
#pragma unroll
    for (int u = 0; u < U1; u++) {
      int dl = (unsigned)pk[u].x >> 20;
      float ws = wt[u] * S1;
      atomicAdd(&accE[dl * 33 + d], __float2int_rn(ws * bflo(g[u])));
      atomicAdd(&accO[dl * 33 + d], __float2int_rn(ws * bfhi(g[u])));
    }
  }
  __syncthreads();
  // F1: in-place relu rows: plane[k&1][node*33+(k>>1)] = relu(dv*(acc+self)+b1[k])
  for (int i = tid; i < SLN * 64; i += BLK) {
    int node = i >> 6, k = i & 63;
    if (node < sn) {
      int v = node0 + node;
      unsigned us = h1s[(size_t)v * 32 + (k >> 1)];  // self (pre-scaled by dinv)
      float self = (k & 1) ? bfhi(us) : bflo(us);
      int* pl = (k & 1) ? accO : accE;
      int idx = node * 33 + (k >> 1);
      float a = pl[idx] * IS1;
      pl[idx] = __float_as_int(fmaxf(dv[node] * (a + self) + bb[k], 0.f));
    }
  }
  __syncthreads();
  // F2: GEMM2, 16 threads per node, 4 node-batches; h2s = dinv[v] * (relu @ W2)
  int j = tid & 15;
  for (int nb = 0; nb < SLN; nb += 16) {
    int node = nb + (tid >> 4);
    float p = 0.f;
#pragma unroll
    for (int k = 0; k < 64; k++) {
      float rv = __int_as_float(((k & 1) ? accO : accE)[node * 33 + (k >> 1)]);
      p += rv * W2s[k * 16 + j];
    }
    p *= dv[node];
    float pp = __shfl_xor(p, 1, 64);
    if (node < sn && (j & 1) == 0)
      h2s[(size_t)(node0 + node) * 8 + (j >> 1)] =
          (unsigned)f2bf(p) | ((unsigned)f2bf(pp) << 16);
  }
}

// ---------------- layer-2: slice-LDS aggregate + bias + log_softmax ---------
// 8-lane subgroup per edge, lane owns dword d (feats 2d,2d+1). acc stride 17.
#define U2 4
__global__ __launch_bounds__(BLK) void k_agg2s(const int* __restrict__ degI,
                                               const int2* __restrict__ bpk,
                                               const int* __restrict__ cur,
                                               const unsigned* __restrict__ h2s,
                                               const float* __restrict__ b2,
                                               float* __restrict__ out, int n) {
  __shared__ int acc2[SLN * 17];
  int tid = threadIdx.x;
  int s = blockIdx.x;
  int node0 = s << SLB;
  int sn = min(SLN, n - node0);
  for (int i = tid; i < SLN * 17; i += BLK) acc2[i] = 0;
  int e0 = s * SCAP;
  int cnt = min(cur[s * CURS], e0 + SCAP) - e0;
  __syncthreads();

  int w = tid >> 6, lane = tid & 63;
  int g = lane >> 3, d = lane & 7;
  unsigned nm1 = (unsigned)(n - 1);
  const int WED2 = 8 * U2;     // 32 edges per wave per iter
  const int STEP2 = 4 * WED2;  // 128 per block-iter
  for (int base = w * WED2; base < cnt; base += STEP2) {
    int2 pk[U2];
    float wt[U2];
    unsigned gg[U2];
#pragma unroll
    for (int u = 0; u < U2; u++) {
      int e = base + 8 * u + g;
      pk[u] = bpk[e0 + min(e, cnt - 1)];
      wt[u] = (e < cnt) ? __int_as_float(pk[u].y) : 0.f;
    }
#pragma unroll
    for (int u = 0; u < U2; u++)
      gg[u] = h2s[(size_t)min((unsigned)(pk[u].x & 0xFFFFF), nm1) * 8 + d];
#pragma unroll
    for (int u = 0; u < U2; u++) {
      int dl = (unsigned)pk[u].x >> 20;
      float ws = wt[u] * S1;
      atomicAdd(&acc2[dl * 17 + 2 * d],     __float2int_rn(ws * bflo(gg[u])));
      atomicAdd(&acc2[dl * 17 + 2 * d + 1], __float2int_rn(ws * bfhi(gg[u])));
    }
  }
  __syncthreads();
  // finalize: 16 threads per node, log_softmax within 16-lane group
  int f = tid & 15;
  for (int nb = 0; nb < SLN; nb += 16) {
    int node = nb + (tid >> 4);
    bool ok = node < sn;
    int v = node0 + min(node, sn - 1);
    float val = 0.f;
    if (ok) {
      float di = rsqrtf(1.0f + degI[v] * IDSC);
      unsigned us = h2s[(size_t)v * 8 + (f >> 1)];  // self (pre-scaled)
      float self = (f & 1) ? bfhi(us) : bflo(us);
      val = di * (acc2[node * 17 + f] * IS1 + self) + b2[f];
    }
    float m = val;
    m = fmaxf(m, __shfl_xor(m, 1, 64));
    m = fmaxf(m, __shfl_xor(m, 2, 64));
    m = fmaxf(m, __shfl_xor(m, 4, 64));
    m = fmaxf(m, __shfl_xor(m, 8, 64));
    float ex = expf(val - m);
    float ssum = ex;
    ssum += __shfl_xor(ssum, 1, 64);
    ssum += __shfl_xor(ssum, 2, 64);
    ssum += __shfl_xor(ssum, 4, 64);
    ssum += __shfl_xor(ssum, 8, 64);
    if (ok) out[(size_t)v * 16 + f] = val - m - logf(ssum);
  }
}

extern "C" void kernel_launch(void* const* d_in, const int* in_sizes, int n_in,
                              void* d_out, int out_size, void* d_ws, size_t ws_size,
                              hipStream_t stream) {
  const float* x  = (const float*)d_in[0];
  const int*   ei = (const int*)d_in[1];   // int32 [2,E]
  const float* ew = (const float*)d_in[2];
  const float* W1 = (const float*)d_in[3];
  const float* b1 = (const float*)d_in[4];
  const float* W2 = (const float*)d_in[5];
  const float* b2 = (const float*)d_in[6];
  float* out = (float*)d_out;

  int n = in_sizes[0] / 128;
  int E = in_sizes[2];
  const int* src = ei;
  const int* dst = ei + E;

  int NS = ((n - 1) >> SLB) + 1;  // 1563 for n=100k
  size_t padE = (size_t)NS * SCAP;

  char* wp = (char*)d_ws;
  auto alloc = [&](size_t bytes) -> char* {
    char* r = wp;
    wp += (bytes + 15) & ~(size_t)15;
    return r;
  };
  int*      cur  = (int*)alloc((size_t)NS * CURS * 4);
  int2*     bpk  = (int2*)alloc(padE * 8);
  int*      degI = (int*)alloc((size_t)n * 4);
  unsigned* h1s  = (unsigned*)alloc((size_t)n * 32 * 4);
  unsigned* h2s  = (unsigned*)alloc((size_t)n * 8 * 4);

  int gB = (E + BLK * EB - 1) / (BLK * EB);  // 1563
  int gZ = (max(n, NS) + BLK - 1) / BLK;

  k_zero<<<gZ, BLK, 0, stream>>>(cur, degI, n, NS);
  k_bucket<<<gB, BLK, 0, stream>>>(src, dst, ew, cur, bpk, degI, n, E);
  k_gemm1<<<(n + 15) / 16, BLK, 0, stream>>>(x, W1, degI, h1s, n);
  k_agg1s<<<NS, BLK, 0, stream>>>(degI, bpk, cur, h1s, b1, W2, h2s, n);
  k_agg2s<<<NS, BLK, 0, stream>>>(degI, bpk, cur, h2s, b2, out, n);
}

// Round 6
// 273.262 us; speedup vs baseline: 1.4672x; 1.4672x over previous
//
#include <hip/hip_runtime.h>
#include <cstdint>

#define BLK 256
#define ABLK 512           // agg kernels: 8 waves/block -> 32 waves/CU at 4 blk/CU
#define EJ 16
#define CHUNK (BLK * EJ)   // 4096 edges per bucket block
#define SLB 6              // slice = 64 nodes
#define SLN 64
#define SCAP 1536          // mean 1024 @ E=1.6M/NS=1563; +16 sigma margin
#define NSMAX 1600         // n <= 102400 supported

// Fixed-point scales for integer atomics (R2/R3 lesson: FP atomicAdd on LDS
// lowers to a CAS retry loop on gfx950 -> 9x stall; int ds_add_u32 is native).
#define S1   2097152.0f        // 2^21, layer-1/2 feature accumulators
#define IS1  (1.0f / 2097152.0f)
#define DSC  16777216.0f       // 2^24, degree accumulator
#define IDSC (1.0f / 16777216.0f)

__device__ inline unsigned short f2bf(float f) {  // RNE
  unsigned u = __float_as_uint(f);
  return (unsigned short)((u + 0x7FFF + ((u >> 16) & 1)) >> 16);
}
__device__ inline float bflo(unsigned u) { return __uint_as_float(u << 16); }
__device__ inline float bfhi(unsigned u) { return __uint_as_float(u & 0xFFFF0000u); }

// ---------------- init per-slice cursors to slice base ----------------
__global__ __launch_bounds__(BLK) void k_zeroC(int* __restrict__ cur, int NS) {
  int s = blockIdx.x * BLK + threadIdx.x;
  if (s < NS) cur[s] = s * SCAP;
}

// ---------------- bucket edges into fixed-capacity slice bins ----------------
// R3-verified structure (<=78us): LDS histogram -> one batched reservation per
// (block,slice) -> LDS-cursor scatter. R4 (single-array+degI fusion, 96us) and
// R5 (per-edge global atomic, 153us) both regressed; do not revisit.
// bpk[p] = { (dstLocal<<20) | src, ew }   (requires n <= 2^20, dstLocal < 64)
__global__ __launch_bounds__(BLK) void k_bucket(const int* __restrict__ src,
                                                const int* __restrict__ dst,
                                                const float* __restrict__ ew,
                                                int* __restrict__ cur,
                                                int2* __restrict__ bpk,
                                                int n, int E, int NS) {
  __shared__ int c[NSMAX], b[NSMAX], o[NSMAX];
  int tid = threadIdx.x;
  for (int i = tid; i < NS; i += BLK) { c[i] = 0; o[i] = 0; }
  __syncthreads();
  int base = blockIdx.x * CHUNK;
  int dloc[EJ];
#pragma unroll
  for (int j = 0; j < EJ; j++) {
    int idx = base + j * BLK + tid;
    int d = -1;
    if (idx < E) {
      d = dst[idx];
      if ((unsigned)d >= (unsigned)n) d = -1;
    }
    dloc[j] = d;
    if (d >= 0) atomicAdd(&c[d >> SLB], 1);
  }
  __syncthreads();
  for (int s = tid; s < NS; s += BLK)
    if (c[s]) b[s] = atomicAdd(&cur[s], c[s]);
  __syncthreads();
#pragma unroll
  for (int j = 0; j < EJ; j++) {
    int idx = base + j * BLK + tid;
    int d = dloc[j];
    if (d >= 0) {
      int s = d >> SLB;
      int p = b[s] + atomicAdd(&o[s], 1);
      p = min(max(p, s * SCAP), (s + 1) * SCAP - 1);  // clamp into slice
      int packed = ((d & (SLN - 1)) << 20) | (src[idx] & 0xFFFFF);
      bpk[p] = make_int2(packed, __float_as_int(ew[idx]));
    }
  }
}

// ---------------- per-slice weighted in-degree -> dinv ----------------------
__global__ __launch_bounds__(BLK) void k_dinv(const int2* __restrict__ bpk,
                                              const int* __restrict__ cur,
                                              float* __restrict__ dinv, int n) {
  __shared__ int wsum[SLN];
  int s = blockIdx.x, tid = threadIdx.x;
  int node0 = s << SLB;
  int e0 = s * SCAP;
  int e1 = min(cur[s], e0 + SCAP);
  if (tid < SLN) wsum[tid] = 0;
  __syncthreads();
  for (int e = e0 + tid; e < e1; e += BLK) {
    int2 pk = bpk[e];
    atomicAdd(&wsum[(unsigned)pk.x >> 20],
              __float2int_rn(__int_as_float(pk.y) * DSC));
  }
  __syncthreads();
  if (tid < SLN && node0 + tid < n)
    dinv[node0 + tid] = rsqrtf(1.0f + wsum[tid] * IDSC);  // deg >= 1 (self loop)
}

// ---------------- GEMM1: h1s[n,64](bf16x2) = dinv * (x[n,128] @ W1[128,64]) --
__global__ __launch_bounds__(BLK) void k_gemm1(const float* __restrict__ x,
                                               const float* __restrict__ W,
                                               const float* __restrict__ dinv,
                                               unsigned* __restrict__ h1s, int n) {
  __shared__ float Ws[128 * 64];
  __shared__ float xs[16][128];
  int tid = threadIdx.x;
  const float4* W4 = (const float4*)W;
  float4* Ws4 = (float4*)Ws;
#pragma unroll
  for (int i = 0; i < 8; i++) Ws4[tid + i * BLK] = W4[tid + i * BLK];
  int row0 = blockIdx.x * 16;
  int nrows = min(16, n - row0);
  const float4* x4 = (const float4*)(x + (size_t)row0 * 128);
  float4* xs4 = (float4*)xs;
  for (int i = tid; i < nrows * 32; i += BLK) xs4[i] = x4[i];
  __syncthreads();
  int col = tid & 63, rg = tid >> 6;  // wave-uniform rg -> xs reads broadcast
  float acc0 = 0.f, acc1 = 0.f, acc2 = 0.f, acc3 = 0.f;
#pragma unroll 4
  for (int k = 0; k < 128; k++) {
    float w = Ws[k * 64 + col];
    acc0 += xs[rg][k] * w;
    acc1 += xs[rg + 4][k] * w;
    acc2 += xs[rg + 8][k] * w;
    acc3 += xs[rg + 12][k] * w;
  }
  int r = row0 + rg;
  int rc0 = min(r, n - 1), rc1 = min(r + 4, n - 1),
      rc2 = min(r + 8, n - 1), rc3 = min(r + 12, n - 1);
  float v0 = acc0 * dinv[rc0], v1 = acc1 * dinv[rc1],
        v2 = acc2 * dinv[rc2], v3 = acc3 * dinv[rc3];
  float p0 = __shfl_xor(v0, 1, 64), p1 = __shfl_xor(v1, 1, 64),
        p2 = __shfl_xor(v2, 1, 64), p3 = __shfl_xor(v3, 1, 64);
  if ((col & 1) == 0) {
    int dw = col >> 1;
    unsigned u0 = (unsigned)f2bf(v0) | ((unsigned)f2bf(p0) << 16);
    unsigned u1 = (unsigned)f2bf(v1) | ((unsigned)f2bf(p1) << 16);
    unsigned u2 = (unsigned)f2bf(v2) | ((unsigned)f2bf(p2) << 16);
    unsigned u3 = (unsigned)f2bf(v3) | ((unsigned)f2bf(p3) << 16);
    if (r < n)      h1s[(size_t)r * 32 + dw]        = u0;
    if (r + 4 < n)  h1s[(size_t)(r + 4) * 32 + dw]  = u1;
    if (r + 8 < n)  h1s[(size_t)(r + 8) * 32 + dw]  = u2;
    if (r + 12 < n) h1s[(size_t)(r + 12) * 32 + dw] = u3;
  }
}

// ---------------- layer-1: slice-LDS aggregate + bias + ReLU + GEMM2 --------
// Block = slice of 64 nodes, 512 threads (R5 lesson: 256-thread blocks at grid
// 1563 cap occupancy at 54%; 8 waves/block -> 32 waves/CU at 4 blocks/CU).
// Half-wave per edge, lane owns dword d (feats 2d,2d+1). Fixed-point int LDS
// accumulators (native ds_add_u32), two planes, stride 33.
#define U1 8
__global__ __launch_bounds__(ABLK) void k_agg1s(const float* __restrict__ dinv,
                                                const int2* __restrict__ bpk,
                                                const int* __restrict__ cur,
                                                const unsigned* __restrict__ h1s,
                                                const float* __restrict__ b1,
                                                const float* __restrict__ W2,
                                                unsigned* __restrict__ h2s, int n) {
  __shared__ int accE[SLN * 33];
  __shared__ int accO[SLN * 33];
  __shared__ float W2s[64 * 16];
  __shared__ float dv[SLN];
  __shared__ float bb[64];
  int tid = threadIdx.x;
  int s = blockIdx.x;
  int node0 = s << SLB;
  int sn = min(SLN, n - node0);
  for (int i = tid; i < SLN * 33; i += ABLK) { accE[i] = 0; accO[i] = 0; }
  for (int i = tid; i < 1024; i += ABLK) W2s[i] = W2[i];
  if (tid < SLN) dv[tid] = (tid < sn) ? dinv[node0 + tid] : 0.f;
  if (tid < 64) bb[tid] = b1[tid];
  int e0 = s * SCAP;
  int cnt = min(cur[s], e0 + SCAP) - e0;
  __syncthreads();

  int w = tid >> 6, half = (tid >> 5) & 1, d = tid & 31;  // w in 0..7
  unsigned nm1 = (unsigned)(n - 1);
  const int WED = 2 * U1;    // 16 edges per wave per iter
  const int STEP = 8 * WED;  // 128 per block-iter (8 waves)
  for (int base = w * WED; base < cnt; base += STEP) {
    int2 pk[U1];
    float wt[U1];
    unsigned g[U1];
#pragma unroll
    for (int u = 0; u < U1; u++) {
      int e = base + 2 * u + half;
      pk[u] = bpk[e0 + min(e, cnt - 1)];  // in-slice clamp (loop ran => cnt>0)
      wt[u] = (e < cnt) ? __int_as_float(pk[u].y) : 0.f;
    }
#pragma unroll
    for (int u = 0; u < U1; u++)
      g[u] = h1s[(size_t)min((unsigned)(pk[u].x & 0xFFFFF), nm1) * 32 + d];
#pragma unroll
    for (int u = 0; u < U1; u++) {
      int dl = (unsigned)pk[u].x >> 20;
      float ws = wt[u] * S1;
      atomicAdd(&accE[dl * 33 + d], __float2int_rn(ws * bflo(g[u])));
      atomicAdd(&accO[dl * 33 + d], __float2int_rn(ws * bfhi(g[u])));
    }
  }
  __syncthreads();
  // F1: in-place relu rows: plane[k&1][node*33+(k>>1)] = relu(dv*(acc+self)+b1[k])
  for (int i = tid; i < SLN * 64; i += ABLK) {
    int node = i >> 6, k = i & 63;
    if (node < sn) {
      int v = node0 + node;
      unsigned us = h1s[(size_t)v * 32 + (k >> 1)];  // self (pre-scaled by dinv)
      float self = (k & 1) ? bfhi(us) : bflo(us);
      int* pl = (k & 1) ? accO : accE;
      int idx = node * 33 + (k >> 1);
      float a = pl[idx] * IS1;
      pl[idx] = __float_as_int(fmaxf(dv[node] * (a + self) + bb[k], 0.f));
    }
  }
  __syncthreads();
  // F2: GEMM2, 16 threads per node, 32 nodes per batch; h2s = dinv * (relu @ W2)
  int j = tid & 15;
  for (int nb = 0; nb < SLN; nb += 32) {
    int node = nb + (tid >> 4);  // 0..31
    float p = 0.f;
#pragma unroll
    for (int k = 0; k < 64; k++) {
      float rv = __int_as_float(((k & 1) ? accO : accE)[node * 33 + (k >> 1)]);
      p += rv * W2s[k * 16 + j];
    }
    p *= dv[node];
    float pp = __shfl_xor(p, 1, 64);
    if (node < sn && (j & 1) == 0)
      h2s[(size_t)(node0 + node) * 8 + (j >> 1)] =
          (unsigned)f2bf(p) | ((unsigned)f2bf(pp) << 16);
  }
}

// ---------------- layer-2: slice-LDS aggregate + bias + log_softmax ---------
// 512 threads. 8-lane subgroup per edge, lane owns dword d. acc stride 17.
#define U2 4
__global__ __launch_bounds__(ABLK) void k_agg2s(const float* __restrict__ dinv,
                                                const int2* __restrict__ bpk,
                                                const int* __restrict__ cur,
                                                const unsigned* __restrict__ h2s,
                                                const float* __restrict__ b2,
                                                float* __restrict__ out, int n) {
  __shared__ int acc2[SLN * 17];
  int tid = threadIdx.x;
  int s = blockIdx.x;
  int node0 = s << SLB;
  int sn = min(SLN, n - node0);
  for (int i = tid; i < SLN * 17; i += ABLK) acc2[i] = 0;
  int e0 = s * SCAP;
  int cnt = min(cur[s], e0 + SCAP) - e0;
  __syncthreads();

  int w = tid >> 6, lane = tid & 63;  // w in 0..7
  int g = lane >> 3, d = lane & 7;
  unsigned nm1 = (unsigned)(n - 1);
  const int WED2 = 8 * U2;     // 32 edges per wave per iter
  const int STEP2 = 8 * WED2;  // 256 per block-iter (8 waves)
  for (int base = w * WED2; base < cnt; base += STEP2) {
    int2 pk[U2];
    float wt[U2];
    unsigned gg[U2];
#pragma unroll
    for (int u = 0; u < U2; u++) {
      int e = base + 8 * u + g;
      pk[u] = bpk[e0 + min(e, cnt - 1)];
      wt[u] = (e < cnt) ? __int_as_float(pk[u].y) : 0.f;
    }
#pragma unroll
    for (int u = 0; u < U2; u++)
      gg[u] = h2s[(size_t)min((unsigned)(pk[u].x & 0xFFFFF), nm1) * 8 + d];
#pragma unroll
    for (int u = 0; u < U2; u++) {
      int dl = (unsigned)pk[u].x >> 20;
      float ws = wt[u] * S1;
      atomicAdd(&acc2[dl * 17 + 2 * d],     __float2int_rn(ws * bflo(gg[u])));
      atomicAdd(&acc2[dl * 17 + 2 * d + 1], __float2int_rn(ws * bfhi(gg[u])));
    }
  }
  __syncthreads();
  // finalize: 16 threads per node, 32 nodes/batch, log_softmax in 16-lane group
  int f = tid & 15;
  for (int nb = 0; nb < SLN; nb += 32) {
    int node = nb + (tid >> 4);  // 0..31
    bool ok = node < sn;
    int v = node0 + min(node, sn - 1);
    float val = 0.f;
    if (ok) {
      float di = dinv[v];
      unsigned us = h2s[(size_t)v * 8 + (f >> 1)];  // self (pre-scaled)
      float self = (f & 1) ? bfhi(us) : bflo(us);
      val = di * (acc2[node * 17 + f] * IS1 + self) + b2[f];
    }
    float m = val;
    m = fmaxf(m, __shfl_xor(m, 1, 64));
    m = fmaxf(m, __shfl_xor(m, 2, 64));
    m = fmaxf(m, __shfl_xor(m, 4, 64));
    m = fmaxf(m, __shfl_xor(m, 8, 64));
    float ex = expf(val - m);
    float ssum = ex;
    ssum += __shfl_xor(ssum, 1, 64);
    ssum += __shfl_xor(ssum, 2, 64);
    ssum += __shfl_xor(ssum, 4, 64);
    ssum += __shfl_xor(ssum, 8, 64);
    if (ok) out[(size_t)v * 16 + f] = val - m - logf(ssum);
  }
}

extern "C" void kernel_launch(void* const* d_in, const int* in_sizes, int n_in,
                              void* d_out, int out_size, void* d_ws, size_t ws_size,
                              hipStream_t stream) {
  const float* x  = (const float*)d_in[0];
  const int*   ei = (const int*)d_in[1];   // int32 [2,E]
  const float* ew = (const float*)d_in[2];
  const float* W1 = (const float*)d_in[3];
  const float* b1 = (const float*)d_in[4];
  const float* W2 = (const float*)d_in[5];
  const float* b2 = (const float*)d_in[6];
  float* out = (float*)d_out;

  int n = in_sizes[0] / 128;
  int E = in_sizes[2];
  const int* src = ei;
  const int* dst = ei + E;

  int NS = ((n - 1) >> SLB) + 1;  // 1563 for n=100k
  size_t padE = (size_t)NS * SCAP;

  char* wp = (char*)d_ws;
  auto alloc = [&](size_t bytes) -> char* {
    char* r = wp;
    wp += (bytes + 15) & ~(size_t)15;
    return r;
  };
  int*      cur  = (int*)alloc((size_t)(NS + 4) * 4);
  int2*     bpk  = (int2*)alloc(padE * 8);
  float*    dinv = (float*)alloc((size_t)n * 4);
  unsigned* h1s  = (unsigned*)alloc((size_t)n * 32 * 4);
  unsigned* h2s  = (unsigned*)alloc((size_t)n * 8 * 4);

  int gC = (E + CHUNK - 1) / CHUNK;  // 391

  k_zeroC<<<(NS + BLK - 1) / BLK, BLK, 0, stream>>>(cur, NS);
  k_bucket<<<gC, BLK, 0, stream>>>(src, dst, ew, cur, bpk, n, E, NS);
  k_dinv<<<NS, BLK, 0, stream>>>(bpk, cur, dinv, n);
  k_gemm1<<<(n + 15) / 16, BLK, 0, stream>>>(x, W1, dinv, h1s, n);
  k_agg1s<<<NS, ABLK, 0, stream>>>(dinv, bpk, cur, h1s, b1, W2, h2s, n);
  k_agg2s<<<NS, ABLK, 0, stream>>>(dinv, bpk, cur, h2s, b2, out, n);
}